// Round 7
// baseline (80.453 us; speedup 1.0000x reference)
//
#include <hip/hip_runtime.h>

typedef __bf16 bf16;
typedef __attribute__((ext_vector_type(4))) __bf16 bf16x4;
typedef __attribute__((ext_vector_type(8))) __bf16 bf16x8;
typedef __attribute__((ext_vector_type(4))) float f32x4;

#define MFMA16(a, b, c) __builtin_amdgcn_mfma_f32_16x16x32_bf16((a), (b), (c), 0, 0, 0)
#define LOG2E 1.4426950408889634f

// KV chunk layout, per (b, kt): 40960 bytes =
//   [0,8192):     K tile [64 q][64 o] bf16, 16B-block swizzle blk^(q&7)
//   [8192,40960): V tile [256 c][64 q] bf16, 16B-block swizzle blk^(c&7)
// Pre-swizzled in GLOBAL so attn stages a LINEAR image (reg->ds_write).

// ---------------------------------------------------------------------------
// Kernel 1: fused V-convert + W prep.
// blocks [0,4096): kf fp32 [b][c][q] -> KV V-part bf16 swizzled.
// blocks [4096,4128): W fp32 -> hi/lo bf16 split (z=0 pre-scaled by log2e).
// ---------------------------------------------------------------------------
__global__ __launch_bounds__(256) void vprep_kernel(const float* __restrict__ kf,
                                                    const float* __restrict__ Wq,
                                                    const float* __restrict__ Wk,
                                                    const int* __restrict__ flag,
                                                    bf16* __restrict__ KV,
                                                    bf16* __restrict__ Wbh,
                                                    bf16* __restrict__ Wbl) {
  const int bid = blockIdx.x, t = threadIdx.x;
  if (bid < 4096) {
    int i = (bid << 8) + t;  // (b, c, q8)
    int q8 = i & 127, c = (i >> 7) & 255, b = i >> 15;
    const float* src = kf + ((size_t)(((b << 8) + c)) << 10) + (q8 << 3);
    float4 f0 = *(const float4*)src;
    float4 f1 = *(const float4*)(src + 4);
    bf16x8 v;
    v[0] = (bf16)f0.x; v[1] = (bf16)f0.y; v[2] = (bf16)f0.z; v[3] = (bf16)f0.w;
    v[4] = (bf16)f1.x; v[5] = (bf16)f1.y; v[6] = (bf16)f1.z; v[7] = (bf16)f1.w;
    int kt = q8 >> 3, qb = q8 & 7;
    char* dst = (char*)KV + (size_t)((b << 4) + kt) * 40960 + 8192 + c * 128 +
                16 * (qb ^ (c & 7));
    *(bf16x8*)dst = v;
  } else {
    int bx = bid - 4096;  // 0..31
    int z = bx >> 4;
    const float* src = (z == 0) ? Wq : ((flag[0] != 0) ? Wq : Wk);
    const float sc = (z == 0) ? LOG2E : 1.0f;  // exp2-domain softmax
    int i = ((((bx & 15) << 8) + t) << 2);
    float4 vv = *(const float4*)(src + i);
    vv.x *= sc; vv.y *= sc; vv.z *= sc; vv.w *= sc;
    bf16x4 hi, lo;
    hi[0] = (bf16)vv.x; lo[0] = (bf16)(vv.x - (float)hi[0]);
    hi[1] = (bf16)vv.y; lo[1] = (bf16)(vv.y - (float)hi[1]);
    hi[2] = (bf16)vv.z; lo[2] = (bf16)(vv.z - (float)hi[2]);
    hi[3] = (bf16)vv.w; lo[3] = (bf16)(vv.w - (float)hi[3]);
    *(bf16x4*)(Wbh + (z << 14) + i) = hi;
    *(bf16x4*)(Wbl + (z << 14) + i) = lo;
  }
}

// ---------------------------------------------------------------------------
// Kernel 2: MFMA projection. z=0 -> Qp (scaled by log2e via W/bias); z=1 ->
// KV K-part swizzled. z=1 B-frags load bf16 straight from packed KV V-region
// (bit-identical to an in-kernel fp32->bf16 cvt; halves HBM read, kills cvt).
// ---------------------------------------------------------------------------
__global__ __launch_bounds__(256) void proj_kernel(const float* __restrict__ qf,
                                                   const bf16* __restrict__ Wbh,
                                                   const bf16* __restrict__ Wbl,
                                                   const float* __restrict__ bq,
                                                   const float* __restrict__ bk,
                                                   const int* __restrict__ flag,
                                                   bf16* __restrict__ Qp,
                                                   bf16* __restrict__ KV) {
  const int b = blockIdx.y, z = blockIdx.z;
  const bf16* Wh = Wbh + z * 16384;
  const bf16* Wl = Wbl + z * 16384;
  const float* bias = z ? (flag[0] ? bq : bk) : bq;

  const int t = threadIdx.x;
  const int w = t >> 6, lane = t & 63;
  const int g = lane >> 4, l16 = lane & 15;
  const int wo = w >> 1, wp = w & 1;
  const int o0 = wo << 5;
  const int pbase = (blockIdx.x << 7) + (wp << 6);

  f32x4 acc[2][4];
#pragma unroll
  for (int ot = 0; ot < 2; ++ot) {
    float4 bv = *(const float4*)(bias + o0 + (ot << 4) + (g << 2));
    if (z == 0) { bv.x *= LOG2E; bv.y *= LOG2E; bv.z *= LOG2E; bv.w *= LOG2E; }
#pragma unroll
    for (int pt = 0; pt < 4; ++pt) acc[ot][pt] = (f32x4){bv.x, bv.y, bv.z, bv.w};
  }

  const float* xb = qf + ((((b << 8) + (g << 3)) << 10) + pbase + l16);
  const char* vsrc = (const char*)KV + (size_t)((b << 4) + (pbase >> 6)) * 40960 +
                     8192 + ((l16 & 7) << 1);
  const bf16* whb = Wh + ((o0 + l16) << 8) + (g << 3);
  const bf16* wlb = Wl + ((o0 + l16) << 8) + (g << 3);

  for (int kk = 0; kk < 8; ++kk) {
    bf16x8 ah[2], al[2];
#pragma unroll
    for (int ot = 0; ot < 2; ++ot) {
      ah[ot] = *(const bf16x8*)(whb + (ot << 12) + (kk << 5));
      al[ot] = *(const bf16x8*)(wlb + (ot << 12) + (kk << 5));
    }
#pragma unroll
    for (int pt = 0; pt < 4; ++pt) {
      bf16x8 xf;
      if (z == 0) {
        const float* xk = xb + (kk << 15);
        float xv[8];
#pragma unroll
        for (int j = 0; j < 8; ++j) xv[j] = xk[(j << 10) + (pt << 4)];
#pragma unroll
        for (int j = 0; j < 8; ++j) xf[j] = (bf16)xv[j];
      } else {
        // c = kk*32 + 8g + j ; byte = c*128 + 16*((2pt + l16>>3) ^ j) (+vsrc)
        const int pb3 = (pt << 1) + (l16 >> 3);
        const char* vp = vsrc + (((kk << 5) + (g << 3)) << 7);
#pragma unroll
        for (int j = 0; j < 8; ++j)
          xf[j] = *(const bf16*)(vp + (j << 7) + ((pb3 ^ j) << 4));
      }
#pragma unroll
      for (int ot = 0; ot < 2; ++ot) {
        acc[ot][pt] = MFMA16(ah[ot], xf, acc[ot][pt]);
        acc[ot][pt] = MFMA16(al[ot], xf, acc[ot][pt]);
      }
    }
  }

#pragma unroll
  for (int ot = 0; ot < 2; ++ot)
#pragma unroll
    for (int pt = 0; pt < 4; ++pt) {
      bf16x4 q4;
#pragma unroll
      for (int r = 0; r < 4; ++r) q4[r] = (bf16)acc[ot][pt][r];
      int p = pbase + (pt << 4) + l16;
      if (z == 0) {
        *(bf16x4*)(Qp + ((((b << 10) + p)) << 6) + o0 + (ot << 4) + (g << 2)) = q4;
      } else {
        int kt = p >> 6, q = p & 63;
        int blk = (o0 >> 3) + (ot << 1) + (g >> 1);
        char* dst = (char*)KV + (size_t)((b << 4) + kt) * 40960 + q * 128 +
                    16 * (blk ^ (q & 7)) + ((g & 1) << 3);
        *(bf16x4*)dst = q4;
      }
    }
}

// ---------------------------------------------------------------------------
// Kernel 3: fused flash attention. grid 512 (XCD-swizzled) x 4 waves.
// Wave (pxg=w>>1, ch=w&1): S+softmax for 32 px (in-lane, dup across ch pair),
// PV for 128 channels. Staging: reg-staged T14 (issue-early global loads ->
// compute -> barrier -> ds_write -> barrier), single 40 KB LDS buffer.
// ---------------------------------------------------------------------------
__global__ __launch_bounds__(256, 2) void attn_kernel(const bf16* __restrict__ KV,
                                                      const bf16* __restrict__ Qp,
                                                      float* __restrict__ out) {
  const int bid = blockIdx.x;
  const int wkid = ((bid & 7) << 6) + (bid >> 3);  // bijective: 512 % 8 == 0
  const int b = wkid >> 4, ptile = wkid & 15;
  const int p0 = ptile << 6;
  const int t = threadIdx.x;
  const int w = t >> 6, lane = t & 63;
  const int u = lane >> 4, l16 = lane & 15;
  const int pxg = w >> 1, ch = w & 1;

  __shared__ __align__(16) unsigned char smem[40960];
  const unsigned char* sK = smem;
  const unsigned char* sV = smem + 8192;

  // Q B-fragments for 2 px sub-groups (col=p, k=o)
  const bf16* qbase = Qp + (((size_t)(b << 10) + p0 + (pxg << 5) + l16) << 6) + (u << 3);
  const bf16x8 qa00 = *(const bf16x8*)qbase;
  const bf16x8 qa01 = *(const bf16x8*)(qbase + 32);
  const bf16x8 qa10 = *(const bf16x8*)(qbase + (16 << 6));
  const bf16x8 qa11 = *(const bf16x8*)(qbase + (16 << 6) + 32);

  const char* src0 = (const char*)KV + (size_t)b * (16 * 40960) + w * 10240 + (lane << 4);
  unsigned char* dst0 = smem + w * 10240 + (lane << 4);

  const int Rb = ((l16 >> 2) << 3) + ((l16 & 3) << 1);  // K row perm base
  const int vsw0 = 16 * (u ^ (l16 & 7));
  const int vsw1 = 16 * ((u + 4) ^ (l16 & 7));

  f32x4 acc[2][8];
#pragma unroll
  for (int sb = 0; sb < 2; ++sb)
#pragma unroll
    for (int ct = 0; ct < 8; ++ct) acc[sb][ct] = (f32x4){0.f, 0.f, 0.f, 0.f};
  float m_[2] = {-1e30f, -1e30f}, l_[2] = {0.f, 0.f};

  // ---- prologue: stage tile 0 ----
  bf16x8 st[10];
#pragma unroll
  for (int i = 0; i < 10; ++i) st[i] = *(const bf16x8*)(src0 + i * 1024);
#pragma unroll
  for (int i = 0; i < 10; ++i) *(bf16x8*)(dst0 + i * 1024) = st[i];
  __syncthreads();

  for (int kt = 0; kt < 16; ++kt) {
    // T14: issue next tile's global loads early; latency hides under compute
    if (kt < 15) {
      const char* src = src0 + (kt + 1) * 40960;
#pragma unroll
      for (int i = 0; i < 10; ++i) st[i] = *(const bf16x8*)(src + i * 1024);
    }
    // ---- S^T = K·Q^T: 8 K-frag reads feed 16 mfma (2 px sub-groups) ----
    f32x4 s[2][4];
#pragma unroll
    for (int qt = 0; qt < 4; ++qt) {
      const int R = Rb + (qt & 1) + ((qt >> 1) << 5);
      const int rb = R * 128;
      bf16x8 k0 = *(const bf16x8*)(sK + rb + 16 * (u ^ (R & 7)));
      bf16x8 k1 = *(const bf16x8*)(sK + rb + 16 * ((u + 4) ^ (R & 7)));
      f32x4 z0 = (f32x4){0.f, 0.f, 0.f, 0.f};
      f32x4 z1 = (f32x4){0.f, 0.f, 0.f, 0.f};
      z0 = MFMA16(k0, qa00, z0);
      s[0][qt] = MFMA16(k1, qa01, z0);
      z1 = MFMA16(k0, qa10, z1);
      s[1][qt] = MFMA16(k1, qa11, z1);
    }
    // ---- softmax (exp2 domain): in-lane reduce + 2 shfl, defer-max ----
    float scv[2];
#pragma unroll
    for (int sb = 0; sb < 2; ++sb) {
      float t0 = fmaxf(fmaxf(s[sb][0][0], s[sb][0][1]), fmaxf(s[sb][0][2], s[sb][0][3]));
      float t1 = fmaxf(fmaxf(s[sb][1][0], s[sb][1][1]), fmaxf(s[sb][1][2], s[sb][1][3]));
      float t2 = fmaxf(fmaxf(s[sb][2][0], s[sb][2][1]), fmaxf(s[sb][2][2], s[sb][2][3]));
      float t3 = fmaxf(fmaxf(s[sb][3][0], s[sb][3][1]), fmaxf(s[sb][3][2], s[sb][3][3]));
      float tm = fmaxf(fmaxf(t0, t1), fmaxf(t2, t3));
      tm = fmaxf(tm, __shfl_xor(tm, 16));
      tm = fmaxf(tm, __shfl_xor(tm, 32));
      float mn = fmaxf(m_[sb], tm);
      if (mn - m_[sb] <= 11.54f) mn = m_[sb];  // defer: P bounded by 2^11.54
      scv[sb] = exp2f(m_[sb] - mn);            // exactly 1.0 when deferred
      m_[sb] = mn;
#pragma unroll
      for (int qt = 0; qt < 4; ++qt)
#pragma unroll
        for (int r = 0; r < 4; ++r) s[sb][qt][r] = exp2f(s[sb][qt][r] - m_[sb]);
      float rs = ((s[sb][0][0] + s[sb][0][1]) + (s[sb][0][2] + s[sb][0][3])) +
                 ((s[sb][1][0] + s[sb][1][1]) + (s[sb][1][2] + s[sb][1][3])) +
                 ((s[sb][2][0] + s[sb][2][1]) + (s[sb][2][2] + s[sb][2][3])) +
                 ((s[sb][3][0] + s[sb][3][1]) + (s[sb][3][2] + s[sb][3][3]));
      rs += __shfl_xor(rs, 16);
      rs += __shfl_xor(rs, 32);
      l_[sb] = l_[sb] * scv[sb] + rs;
    }
    if (__any((scv[0] != 1.f) || (scv[1] != 1.f))) {
#pragma unroll
      for (int sb = 0; sb < 2; ++sb)
#pragma unroll
        for (int ct = 0; ct < 8; ++ct) {
          acc[sb][ct][0] *= scv[sb]; acc[sb][ct][1] *= scv[sb];
          acc[sb][ct][2] *= scv[sb]; acc[sb][ct][3] *= scv[sb];
        }
    }
    // ---- P -> bf16 B-fragments, fully in-lane (K-permutation payoff) ----
    bf16x8 pb[2][2];
#pragma unroll
    for (int sb = 0; sb < 2; ++sb)
#pragma unroll
      for (int r = 0; r < 4; ++r) {
        pb[sb][0][2 * r] = (bf16)s[sb][0][r];
        pb[sb][0][2 * r + 1] = (bf16)s[sb][1][r];
        pb[sb][1][2 * r] = (bf16)s[sb][2][r];
        pb[sb][1][2 * r + 1] = (bf16)s[sb][3][r];
      }
    // ---- PV: 16 V-frag reads feed 32 mfma (this wave's 128-ch half) ----
#pragma unroll
    for (int ct = 0; ct < 8; ++ct) {
      const unsigned char* vrow = sV + ((ch << 7) + (ct << 4) + l16) * 128;
      bf16x8 v0 = *(const bf16x8*)(vrow + vsw0);
      bf16x8 v1 = *(const bf16x8*)(vrow + vsw1);
      acc[0][ct] = MFMA16(v0, pb[0][0], acc[0][ct]);
      acc[0][ct] = MFMA16(v1, pb[0][1], acc[0][ct]);
      acc[1][ct] = MFMA16(v0, pb[1][0], acc[1][ct]);
      acc[1][ct] = MFMA16(v1, pb[1][1], acc[1][ct]);
    }
    __syncthreads();  // all LDS reads of current tile done
    if (kt < 15) {
#pragma unroll
      for (int i = 0; i < 10; ++i) *(bf16x8*)(dst0 + i * 1024) = st[i];
      __syncthreads();  // next tile published
    }
  }

  // ---- epilogue: per-lane normalize, direct stores (16-lane 64B runs) ----
#pragma unroll
  for (int sb = 0; sb < 2; ++sb) {
    const float inv = 1.f / l_[sb];
    const int p = p0 + (pxg << 5) + (sb << 4) + l16;
    float* ob = out + ((size_t)b << 18) + p;
#pragma unroll
    for (int ct = 0; ct < 8; ++ct)
#pragma unroll
      for (int r = 0; r < 4; ++r) {
        int c = (ch << 7) + (ct << 4) + (u << 2) + r;
        ob[(size_t)c << 10] = acc[sb][ct][r] * inv;
      }
  }
}

// ---------------------------------------------------------------------------
extern "C" void kernel_launch(void* const* d_in, const int* in_sizes, int n_in,
                              void* d_out, int out_size, void* d_ws, size_t ws_size,
                              hipStream_t stream) {
  const float* qf = (const float*)d_in[0];
  const float* kf = (const float*)d_in[1];
  const float* Wq = (const float*)d_in[2];
  const float* bq = (const float*)d_in[3];
  const float* Wk = (const float*)d_in[4];
  const float* bk = (const float*)d_in[5];
  // d_in[6] = vis_CA (unused)
  const int* flag = (const int*)d_in[7];  // same_WqWk
  float* out = (float*)d_out;

  char* ws = (char*)d_ws;
  bf16* Qp = (bf16*)ws;                          // 4 MiB: [32][1024][64] bf16
  bf16* Wbh = (bf16*)(ws + (4u << 20));          // 64 KiB
  bf16* Wbl = (bf16*)(ws + (4u << 20) + 65536);  // 64 KiB
  bf16* KV = (bf16*)(ws + (5u << 20));           // 20 MiB: [32][16] x 40960B chunks

  vprep_kernel<<<4128, 256, 0, stream>>>(kf, Wq, Wk, flag, KV, Wbh, Wbl);
  proj_kernel<<<dim3(8, 32, 2), 256, 0, stream>>>(qf, Wbh, Wbl, bq, bk, flag, Qp, KV);
  attn_kernel<<<512, 256, 0, stream>>>(KV, Qp, out);
}

// Round 8
// 70.474 us; speedup vs baseline: 1.1416x; 1.1416x over previous
//
#include <hip/hip_runtime.h>

typedef __bf16 bf16;
typedef __attribute__((ext_vector_type(4))) __bf16 bf16x4;
typedef __attribute__((ext_vector_type(8))) __bf16 bf16x8;
typedef __attribute__((ext_vector_type(4))) float f32x4;
typedef unsigned int u32;

#define MFMA16(a, b, c) __builtin_amdgcn_mfma_f32_16x16x32_bf16((a), (b), (c), 0, 0, 0)
#define LOG2E 1.4426950408889634f
#define AS1 __attribute__((address_space(1)))
#define AS3 __attribute__((address_space(3)))
// 16B direct global->LDS DMA; LDS dest = wave-uniform base + lane*16
#define GLL16(g, l) __builtin_amdgcn_global_load_lds((const AS1 u32*)(g), (AS3 u32*)(l), 16, 0, 0)

// KV chunk layout, per (b, kt): 40960 bytes =
//   [0,8192):     K tile [64 q][64 o] bf16, 16B-block swizzle blk^(q&7)
//   [8192,40960): V tile [256 c][64 q] bf16, 16B-block swizzle blk^(c&7)
// Pre-swizzled in GLOBAL so attn stages a LINEAR image via global_load_lds.

// ---------------------------------------------------------------------------
// Kernel 1: fused V-convert + W prep.
// blocks [0,4096): kf fp32 [b][c][q] -> KV V-part bf16 swizzled.
// blocks [4096,4128): W fp32 -> hi/lo bf16 split (z=0 pre-scaled by log2e).
// ---------------------------------------------------------------------------
__global__ __launch_bounds__(256) void vprep_kernel(const float* __restrict__ kf,
                                                    const float* __restrict__ Wq,
                                                    const float* __restrict__ Wk,
                                                    const int* __restrict__ flag,
                                                    bf16* __restrict__ KV,
                                                    bf16* __restrict__ Wbh,
                                                    bf16* __restrict__ Wbl) {
  const int bid = blockIdx.x, t = threadIdx.x;
  if (bid < 4096) {
    int i = (bid << 8) + t;  // (b, c, q8)
    int q8 = i & 127, c = (i >> 7) & 255, b = i >> 15;
    const float* src = kf + ((size_t)(((b << 8) + c)) << 10) + (q8 << 3);
    float4 f0 = *(const float4*)src;
    float4 f1 = *(const float4*)(src + 4);
    bf16x8 v;
    v[0] = (bf16)f0.x; v[1] = (bf16)f0.y; v[2] = (bf16)f0.z; v[3] = (bf16)f0.w;
    v[4] = (bf16)f1.x; v[5] = (bf16)f1.y; v[6] = (bf16)f1.z; v[7] = (bf16)f1.w;
    int kt = q8 >> 3, qb = q8 & 7;
    char* dst = (char*)KV + (size_t)((b << 4) + kt) * 40960 + 8192 + c * 128 +
                16 * (qb ^ (c & 7));
    *(bf16x8*)dst = v;
  } else {
    int bx = bid - 4096;  // 0..31
    int z = bx >> 4;
    const float* src = (z == 0) ? Wq : ((flag[0] != 0) ? Wq : Wk);
    const float sc = (z == 0) ? LOG2E : 1.0f;  // exp2-domain softmax
    int i = ((((bx & 15) << 8) + t) << 2);
    float4 vv = *(const float4*)(src + i);
    vv.x *= sc; vv.y *= sc; vv.z *= sc; vv.w *= sc;
    bf16x4 hi, lo;
    hi[0] = (bf16)vv.x; lo[0] = (bf16)(vv.x - (float)hi[0]);
    hi[1] = (bf16)vv.y; lo[1] = (bf16)(vv.y - (float)hi[1]);
    hi[2] = (bf16)vv.z; lo[2] = (bf16)(vv.z - (float)hi[2]);
    hi[3] = (bf16)vv.w; lo[3] = (bf16)(vv.w - (float)hi[3]);
    *(bf16x4*)(Wbh + (z << 14) + i) = hi;
    *(bf16x4*)(Wbl + (z << 14) + i) = lo;
  }
}

// ---------------------------------------------------------------------------
// Kernel 2: MFMA projection. z=0 -> Qp (scaled by log2e via W/bias); z=1 ->
// KV K-part swizzled. z=1 B-frags load bf16 straight from packed KV V-region
// (bit-identical to in-kernel fp32->bf16 cvt; halves HBM read, kills cvt).
// ---------------------------------------------------------------------------
__global__ __launch_bounds__(256) void proj_kernel(const float* __restrict__ qf,
                                                   const bf16* __restrict__ Wbh,
                                                   const bf16* __restrict__ Wbl,
                                                   const float* __restrict__ bq,
                                                   const float* __restrict__ bk,
                                                   const int* __restrict__ flag,
                                                   bf16* __restrict__ Qp,
                                                   bf16* __restrict__ KV) {
  const int b = blockIdx.y, z = blockIdx.z;
  const bf16* Wh = Wbh + z * 16384;
  const bf16* Wl = Wbl + z * 16384;
  const float* bias = z ? (flag[0] ? bq : bk) : bq;

  const int t = threadIdx.x;
  const int w = t >> 6, lane = t & 63;
  const int g = lane >> 4, l16 = lane & 15;
  const int wo = w >> 1, wp = w & 1;
  const int o0 = wo << 5;
  const int pbase = (blockIdx.x << 7) + (wp << 6);

  f32x4 acc[2][4];
#pragma unroll
  for (int ot = 0; ot < 2; ++ot) {
    float4 bv = *(const float4*)(bias + o0 + (ot << 4) + (g << 2));
    if (z == 0) { bv.x *= LOG2E; bv.y *= LOG2E; bv.z *= LOG2E; bv.w *= LOG2E; }
#pragma unroll
    for (int pt = 0; pt < 4; ++pt) acc[ot][pt] = (f32x4){bv.x, bv.y, bv.z, bv.w};
  }

  const float* xb = qf + ((((b << 8) + (g << 3)) << 10) + pbase + l16);
  const char* vsrc = (const char*)KV + (size_t)((b << 4) + (pbase >> 6)) * 40960 +
                     8192 + ((l16 & 7) << 1);
  const bf16* whb = Wh + ((o0 + l16) << 8) + (g << 3);
  const bf16* wlb = Wl + ((o0 + l16) << 8) + (g << 3);

  for (int kk = 0; kk < 8; ++kk) {
    bf16x8 ah[2], al[2];
#pragma unroll
    for (int ot = 0; ot < 2; ++ot) {
      ah[ot] = *(const bf16x8*)(whb + (ot << 12) + (kk << 5));
      al[ot] = *(const bf16x8*)(wlb + (ot << 12) + (kk << 5));
    }
#pragma unroll
    for (int pt = 0; pt < 4; ++pt) {
      bf16x8 xf;
      if (z == 0) {
        const float* xk = xb + (kk << 15);
        float xv[8];
#pragma unroll
        for (int j = 0; j < 8; ++j) xv[j] = xk[(j << 10) + (pt << 4)];
#pragma unroll
        for (int j = 0; j < 8; ++j) xf[j] = (bf16)xv[j];
      } else {
        // c = kk*32 + 8g + j ; byte = c*128 + 16*((2pt + l16>>3) ^ j) (+vsrc)
        const int pb3 = (pt << 1) + (l16 >> 3);
        const char* vp = vsrc + (((kk << 5) + (g << 3)) << 7);
#pragma unroll
        for (int j = 0; j < 8; ++j)
          xf[j] = *(const bf16*)(vp + (j << 7) + ((pb3 ^ j) << 4));
      }
#pragma unroll
      for (int ot = 0; ot < 2; ++ot) {
        acc[ot][pt] = MFMA16(ah[ot], xf, acc[ot][pt]);
        acc[ot][pt] = MFMA16(al[ot], xf, acc[ot][pt]);
      }
    }
  }

#pragma unroll
  for (int ot = 0; ot < 2; ++ot)
#pragma unroll
    for (int pt = 0; pt < 4; ++pt) {
      bf16x4 q4;
#pragma unroll
      for (int r = 0; r < 4; ++r) q4[r] = (bf16)acc[ot][pt][r];
      int p = pbase + (pt << 4) + l16;
      if (z == 0) {
        *(bf16x4*)(Qp + ((((b << 10) + p)) << 6) + o0 + (ot << 4) + (g << 2)) = q4;
      } else {
        int kt = p >> 6, q = p & 63;
        int blk = (o0 >> 3) + (ot << 1) + (g >> 1);
        char* dst = (char*)KV + (size_t)((b << 4) + kt) * 40960 + q * 128 +
                    16 * (blk ^ (q & 7)) + ((g & 1) << 3);
        *(bf16x4*)dst = q4;
      }
    }
}

// ---------------------------------------------------------------------------
// Kernel 3: fused flash attention. grid 512 (XCD-swizzled) x 4 waves.
// R4 partition: wave w owns 16 px [p0+16w, +16) end-to-end (S+softmax+PV,
// all 256 channels, single softmax — no duplication).
// Staging: global_load_lds double-buffer (pre-swizzled KV chunks), ONE
// vmcnt(0)+barrier per iter.
// ---------------------------------------------------------------------------
__global__ __launch_bounds__(256, 2) void attn_kernel(const bf16* __restrict__ KV,
                                                      const bf16* __restrict__ Qp,
                                                      float* __restrict__ out) {
  const int bid = blockIdx.x;
  const int wkid = ((bid & 7) << 6) + (bid >> 3);  // bijective: 512 % 8 == 0
  const int b = wkid >> 4, ptile = wkid & 15;
  const int p0 = ptile << 6;
  const int t = threadIdx.x;
  const int w = t >> 6, lane = t & 63;
  const int u = lane >> 4, l16 = lane & 15;
  const int p = p0 + (w << 4) + l16;  // this lane's output pixel (D col)

  __shared__ __align__(16) unsigned char smem[2][40960];

  // Q B-fragments (col=p, k=o=8u+j / 32+8u+j)
  const bf16* qb = Qp + (((size_t)(b << 10) + p) << 6) + (u << 3);
  const bf16x8 qa0 = *(const bf16x8*)qb;
  const bf16x8 qa1 = *(const bf16x8*)(qb + 32);

  const char* chunk0 = (const char*)KV + (size_t)b * (16 * 40960);
  const int Rb = ((l16 >> 2) << 3) + ((l16 & 3) << 1);  // K row perm base
  const int vsw0 = 16 * (u ^ (l16 & 7));
  const int vsw1 = 16 * ((u + 4) ^ (l16 & 7));

  f32x4 acc[16];  // D[c][p]: c = 16ct + 4u + r
#pragma unroll
  for (int i = 0; i < 16; ++i) acc[i] = (f32x4){0.f, 0.f, 0.f, 0.f};
  float m_ = -1e30f, l_ = 0.f;

  // ---- stage tile 0 ----
  {
    const char* g = chunk0 + w * 10240 + (lane << 4);
    unsigned char* l = smem[0] + w * 10240;
#pragma unroll
    for (int op = 0; op < 10; ++op) GLL16(g + op * 1024, l + op * 1024);
  }
  asm volatile("s_waitcnt vmcnt(0)" ::: "memory");
  __syncthreads();

  int cur = 0;
  for (int kt = 0; kt < 16; ++kt) {
    // prefetch next tile into other buffer (in flight during compute)
    if (kt < 15) {
      const char* g = chunk0 + (kt + 1) * 40960 + w * 10240 + (lane << 4);
      unsigned char* l = smem[cur ^ 1] + w * 10240;
#pragma unroll
      for (int op = 0; op < 10; ++op) GLL16(g + op * 1024, l + op * 1024);
    }
    const unsigned char* sK = smem[cur];
    const unsigned char* sV = smem[cur] + 8192;

    // ---- S^T = K·Q^T (8 mfma, permuted K rows from swizzled LDS) ----
    f32x4 s[4];
#pragma unroll
    for (int qt = 0; qt < 4; ++qt) {
      const int R = Rb + (qt & 1) + ((qt >> 1) << 5);
      const int rb = R * 128;
      bf16x8 k0 = *(const bf16x8*)(sK + rb + 16 * (u ^ (R & 7)));
      bf16x8 k1 = *(const bf16x8*)(sK + rb + 16 * ((u + 4) ^ (R & 7)));
      f32x4 z = (f32x4){0.f, 0.f, 0.f, 0.f};
      z = MFMA16(k0, qa0, z);
      s[qt] = MFMA16(k1, qa1, z);
    }
    // ---- softmax (exp2 domain): in-lane 16-val reduce + 2 shfl, defer-max ----
    float tq0 = fmaxf(fmaxf(s[0][0], s[0][1]), fmaxf(s[0][2], s[0][3]));
    float tq1 = fmaxf(fmaxf(s[1][0], s[1][1]), fmaxf(s[1][2], s[1][3]));
    float tq2 = fmaxf(fmaxf(s[2][0], s[2][1]), fmaxf(s[2][2], s[2][3]));
    float tq3 = fmaxf(fmaxf(s[3][0], s[3][1]), fmaxf(s[3][2], s[3][3]));
    float tm = fmaxf(fmaxf(tq0, tq1), fmaxf(tq2, tq3));
    tm = fmaxf(tm, __shfl_xor(tm, 16));
    tm = fmaxf(tm, __shfl_xor(tm, 32));
    float mn = fmaxf(m_, tm);
    if (mn - m_ <= 11.54f) mn = m_;  // defer: P bounded by 2^11.54 = e^8
    float sc = exp2f(m_ - mn);       // exactly 1.0 when deferred
    m_ = mn;
#pragma unroll
    for (int qt = 0; qt < 4; ++qt)
#pragma unroll
      for (int r = 0; r < 4; ++r) s[qt][r] = exp2f(s[qt][r] - m_);
    float rs = ((s[0][0] + s[0][1]) + (s[0][2] + s[0][3])) +
               ((s[1][0] + s[1][1]) + (s[1][2] + s[1][3])) +
               ((s[2][0] + s[2][1]) + (s[2][2] + s[2][3])) +
               ((s[3][0] + s[3][1]) + (s[3][2] + s[3][3]));
    rs += __shfl_xor(rs, 16);
    rs += __shfl_xor(rs, 32);
    l_ = l_ * sc + rs;
    if (__any(sc != 1.f)) {
#pragma unroll
      for (int i = 0; i < 16; ++i) {
        acc[i][0] *= sc; acc[i][1] *= sc; acc[i][2] *= sc; acc[i][3] *= sc;
      }
    }
    // ---- P -> bf16 B-fragments fully in-lane (K-permutation payoff) ----
    bf16x8 pb0, pb1;
#pragma unroll
    for (int r = 0; r < 4; ++r) {
      pb0[2 * r] = (bf16)s[0][r];
      pb0[2 * r + 1] = (bf16)s[1][r];
      pb1[2 * r] = (bf16)s[2][r];
      pb1[2 * r + 1] = (bf16)s[3][r];
    }
    // ---- PV: 32 V-frag reads feed 32 mfma (all 256 channels) ----
#pragma unroll
    for (int ct = 0; ct < 16; ++ct) {
      const unsigned char* vrow = sV + (((ct << 4) + l16) << 7);
      bf16x8 v0 = *(const bf16x8*)(vrow + vsw0);
      bf16x8 v1 = *(const bf16x8*)(vrow + vsw1);
      acc[ct] = MFMA16(v0, pb0, acc[ct]);
      acc[ct] = MFMA16(v1, pb1, acc[ct]);
    }
    if (kt < 15) {
      asm volatile("s_waitcnt vmcnt(0)" ::: "memory");
      __syncthreads();  // next tile landed; everyone done reading cur
      cur ^= 1;
    }
  }

  // ---- epilogue: per-lane normalize, direct stores (16-lane 64B runs) ----
  const float inv = 1.f / l_;
  float* ob = out + ((size_t)b << 18) + p;
#pragma unroll
  for (int ct = 0; ct < 16; ++ct)
#pragma unroll
    for (int r = 0; r < 4; ++r) {
      int c = (ct << 4) + (u << 2) + r;
      ob[(size_t)c << 10] = acc[ct][r] * inv;
    }
}

// ---------------------------------------------------------------------------
extern "C" void kernel_launch(void* const* d_in, const int* in_sizes, int n_in,
                              void* d_out, int out_size, void* d_ws, size_t ws_size,
                              hipStream_t stream) {
  const float* qf = (const float*)d_in[0];
  const float* kf = (const float*)d_in[1];
  const float* Wq = (const float*)d_in[2];
  const float* bq = (const float*)d_in[3];
  const float* Wk = (const float*)d_in[4];
  const float* bk = (const float*)d_in[5];
  // d_in[6] = vis_CA (unused)
  const int* flag = (const int*)d_in[7];  // same_WqWk
  float* out = (float*)d_out;

  char* ws = (char*)d_ws;
  bf16* Qp = (bf16*)ws;                          // 4 MiB: [32][1024][64] bf16
  bf16* Wbh = (bf16*)(ws + (4u << 20));          // 64 KiB
  bf16* Wbl = (bf16*)(ws + (4u << 20) + 65536);  // 64 KiB
  bf16* KV = (bf16*)(ws + (5u << 20));           // 20 MiB: [32][16] x 40960B chunks

  vprep_kernel<<<4128, 256, 0, stream>>>(kf, Wq, Wk, flag, KV, Wbh, Wbl);
  proj_kernel<<<dim3(8, 32, 2), 256, 0, stream>>>(qf, Wbh, Wbl, bq, bk, flag, Qp, KV);
  attn_kernel<<<512, 256, 0, stream>>>(KV, Qp, out);
}